// Round 7
// baseline (159.497 us; speedup 1.0000x reference)
//
#include <hip/hip_runtime.h>
#include <cstdint>
#include <cstddef>

#define N_ROWS 3456   // 16*216 chunks
#define C_DIM 256
#define K_CB 1024
#define B_SZ 16
#define SPATIAL 216
#define VOX 13824     // 24*24*24
#define NCH 32
#define NSB 54        // k_post blocks (64 rows each)

typedef __attribute__((ext_vector_type(16))) float f32x16;
typedef __attribute__((ext_vector_type(8))) short bf16x8;

__device__ __forceinline__ unsigned short f2bf_rne(float f) {
    unsigned int u = __float_as_uint(f);
    u += 0x7FFFu + ((u >> 16) & 1u);
    return (unsigned short)(u >> 16);
}
__device__ __forceinline__ float bf2f(unsigned short h) {
    unsigned int u = ((unsigned int)h) << 16;
    return __uint_as_float(u);
}

// Swizzled fragment layout: element (row n, col c) of a [rows x 256] matrix
// lives at  strip(n>>5)*8192 + (c>>3)*256 + (n&31)*8 + (c&7).
// A wave's MFMA fragment for (strip s, k-step s16) is then the contiguous
// 1 KB block  [s*8192 + s16*512 + lane*8 .. +8)  -- 16 B/lane, coalesced.
__device__ __forceinline__ size_t swz(int n, int c) {
    return (size_t)(n >> 5) * 8192 + (size_t)((c >> 3) * 256) + (size_t)((n & 31) * 8) + (c & 7);
}

// ---------------- K1: fused preprocessing: patterns + init + cb/z norm+split
// grid: [0,864) patterns ; [864,1888) codebook ; [1888,5344) z rows
__global__ __launch_bounds__(256) void k_pre(
        const float* __restrict__ in, const float* __restrict__ cb,
        const float* __restrict__ ze,
        unsigned long long* __restrict__ pats,
        float* __restrict__ scal,
        float* __restrict__ en,
        unsigned short* __restrict__ ehi, unsigned short* __restrict__ elo,
        unsigned short* __restrict__ zhi, unsigned short* __restrict__ zlo) {
    int bid = blockIdx.x;
    int t = threadIdx.x;
    if (bid < 864) {
        if (bid == 0 && t < 16) scal[t] = 0.0f;   // scal[0..7] + done counter
        int v = bid * 256 + t;
        int b = v / VOX;
        int r = v % VOX;
        const float* p = in + (size_t)b * NCH * VOX + r;
        float v0 = p[0];
        float mx = -INFINITY;
#pragma unroll
        for (int c = 1; c < NCH; ++c) mx = fmaxf(mx, p[(size_t)c * VOX]);
        unsigned long long m = __ballot(mx > v0);
        if ((t & 63) == 0) pats[v >> 6] = m;
        return;
    }
    __shared__ float ws[4];
    if (bid < 1888) {
        int k = bid - 864, c = t;
        float v = cb[k * C_DIM + c];
        float ss = v * v;
#pragma unroll
        for (int off = 32; off > 0; off >>= 1) ss += __shfl_down(ss, off, 64);
        if ((c & 63) == 0) ws[c >> 6] = ss;
        __syncthreads();
        float nrm = fmaxf(sqrtf(ws[0] + ws[1] + ws[2] + ws[3]), 1e-12f);
        float o = v / nrm;
        en[k * C_DIM + c] = o;
        unsigned short h = f2bf_rne(o);
        size_t off = swz(k, c);
        ehi[off] = h;
        elo[off] = f2bf_rne(o - bf2f(h));
    } else {
        int n = bid - 1888, c = t;
        int b = n / SPATIAL, s = n % SPATIAL;
        float v = ze[((size_t)(b * C_DIM + c)) * SPATIAL + s];
        float ss = v * v;
#pragma unroll
        for (int off = 32; off > 0; off >>= 1) ss += __shfl_down(ss, off, 64);
        if ((c & 63) == 0) ws[c >> 6] = ss;
        __syncthreads();
        float nrm = fmaxf(sqrtf(ws[0] + ws[1] + ws[2] + ws[3]), 1e-12f);
        float o = v / nrm;
        unsigned short h = f2bf_rne(o);
        size_t off = swz(n, c);
        zhi[off] = h;
        zlo[off] = f2bf_rne(o - bf2f(h));
    }
}

// ------------- K2: fat kernel: affinity GEMM (bf16x3 MFMA) + hamming Gram.
// Barrier-free, LDS-free: all fragments loaded directly from the swizzled
// global buffers (coalesced 16 B/lane), latency hidden by unrolled ILP.
// blocks [0,432): gemm 64x128 tiles; [432,810): ham upper-tri 128x128 tiles
__global__ __launch_bounds__(128) void k_mid(
        const unsigned short* __restrict__ zhi, const unsigned short* __restrict__ zlo,
        const unsigned short* __restrict__ ehi, const unsigned short* __restrict__ elo,
        const unsigned long long* __restrict__ pats,
        float* __restrict__ aff, float* __restrict__ scal) {
    int t = threadIdx.x;
    int w = t >> 6, lane = t & 63;
    int bid = blockIdx.x;
    const bf16x8* __restrict__ Zh = (const bf16x8*)zhi;   // [strip][1024 chunks]
    const bf16x8* __restrict__ Zl = (const bf16x8*)zlo;
    const bf16x8* __restrict__ Eh = (const bf16x8*)ehi;
    const bf16x8* __restrict__ El = (const bf16x8*)elo;

    if (bid < 432) {
        // ----- GEMM branch: aff = z @ en^T with hi/lo error compensation
        int ib = bid % 54, jb = bid / 54;
        int i0 = ib * 64, j0 = jb * 128;
        int sa = ib * 2;               // A strips (64 rows = 2 strips)
        int sb = jb * 4 + w * 2;       // B strips for this wave (2 of 4)

        f32x16 acc[2][2];
#pragma unroll
        for (int r = 0; r < 2; ++r)
#pragma unroll
            for (int q = 0; q < 2; ++q)
#pragma unroll
                for (int e = 0; e < 16; ++e) acc[r][q][e] = 0.0f;

#pragma unroll
        for (int s16 = 0; s16 < 16; ++s16) {    // 16 k-steps of 16
            int u = s16 * 64 + lane;
            bf16x8 ah[2], al[2], bh[2], bl[2];
#pragma unroll
            for (int r = 0; r < 2; ++r) {
                ah[r] = Zh[(size_t)(sa + r) * 1024 + u];
                al[r] = Zl[(size_t)(sa + r) * 1024 + u];
            }
#pragma unroll
            for (int q = 0; q < 2; ++q) {
                bh[q] = Eh[(size_t)(sb + q) * 1024 + u];
                bl[q] = El[(size_t)(sb + q) * 1024 + u];
            }
#pragma unroll
            for (int r = 0; r < 2; ++r)
#pragma unroll
                for (int q = 0; q < 2; ++q) {
                    acc[r][q] = __builtin_amdgcn_mfma_f32_32x32x16_bf16(ah[r], bh[q], acc[r][q], 0, 0, 0);
                    acc[r][q] = __builtin_amdgcn_mfma_f32_32x32x16_bf16(ah[r], bl[q], acc[r][q], 0, 0, 0);
                    acc[r][q] = __builtin_amdgcn_mfma_f32_32x32x16_bf16(al[r], bh[q], acc[r][q], 0, 0, 0);
                }
        }
        // C/D layout (m74/m101): col=lane&31, row=(g&3)+8*(g>>2)+4*(lane>>5)
#pragma unroll
        for (int r = 0; r < 2; ++r)
#pragma unroll
            for (int q = 0; q < 2; ++q)
#pragma unroll
                for (int g = 0; g < 16; ++g) {
                    int row = i0 + r * 32 + (g & 3) + 8 * (g >> 2) + 4 * (lane >> 5);
                    int col = j0 + w * 64 + q * 32 + (lane & 31);
                    aff[(size_t)row * K_CB + col] = acc[r][q][g];
                }
        return;
    }

    // ----- HAM branch: pairwise Gram, upper-triangular 128x128 tiles
    int hb = bid - 432;              // 0..377
    int ti = 0, rem = hb;
    while (rem >= 27 - ti) { rem -= 27 - ti; ++ti; }
    int tj = ti + rem;
    int i0 = ti * 128, j0 = tj * 128;
    float factor = (ti == tj) ? 1.0f : 2.0f;
    int si = ti * 4 + w * 2;         // A strips for this wave (2 of 4)
    int sj = tj * 4;                 // B strips (4)

    f32x16 acc[2][4];
#pragma unroll
    for (int a = 0; a < 2; ++a)
#pragma unroll
        for (int b = 0; b < 4; ++b)
#pragma unroll
            for (int e = 0; e < 16; ++e) acc[a][b][e] = 0.0f;

#pragma unroll
    for (int s16 = 0; s16 < 16; ++s16) {
        int u = s16 * 64 + lane;
        bf16x8 a0 = Zh[(size_t)si * 1024 + u];
        bf16x8 a1 = Zh[(size_t)(si + 1) * 1024 + u];
        bf16x8 bf[4];
#pragma unroll
        for (int c = 0; c < 4; ++c)
            bf[c] = Zh[(size_t)(sj + c) * 1024 + u];
#pragma unroll
        for (int c = 0; c < 4; ++c) {
            acc[0][c] = __builtin_amdgcn_mfma_f32_32x32x16_bf16(a0, bf[c], acc[0][c], 0, 0, 0);
            acc[1][c] = __builtin_amdgcn_mfma_f32_32x32x16_bf16(a1, bf[c], acc[1][c], 0, 0, 0);
        }
    }

    unsigned long long pj[4];
#pragma unroll
    for (int c = 0; c < 4; ++c) pj[c] = pats[j0 + c * 32 + (lane & 31)];

    float sW = 0.0f, sD = 0.0f;
#pragma unroll
    for (int r = 0; r < 2; ++r) {
        int ibase = i0 + w * 64 + r * 32 + 4 * (lane >> 5);
#pragma unroll
        for (int g = 0; g < 16; ++g) {
            int gi = ibase + (g & 3) + 8 * (g >> 2);
            unsigned long long pi = pats[gi];
#pragma unroll
            for (int c = 0; c < 4; ++c) {
                int gj = j0 + c * 32 + (lane & 31);
                int pop = __popcll(pi ^ pj[c]);
                float wgt = (pop <= 5 && gi != gj) ? (1.0f - (float)pop * 0.015625f) : 0.0f;
                sW += wgt;
                sD += wgt * acc[r][c][g];
            }
        }
    }
#pragma unroll
    for (int off = 32; off > 0; off >>= 1) {
        sW += __shfl_down(sW, off, 64);
        sD += __shfl_down(sD, off, 64);
    }
    if (lane == 0) {
        atomicAdd(&scal[2], factor * sW);
        atomicAdd(&scal[3], factor * sD);
    }
}

// -------- K3: stats + z_q gather/scatter + final loss (last-block reduce)
#define ZQS 257
__global__ __launch_bounds__(256) void k_post(
        const float* __restrict__ aff, const float* __restrict__ en,
        float* __restrict__ avgp_part, float* __restrict__ scal,
        float* __restrict__ out) {
    __shared__ float lps[4][K_CB];       // 16 KB
    __shared__ float zq[64 * ZQS];       // 65.8 KB transpose buffer
    __shared__ float lsc[8];
    __shared__ float ws4[4];
    __shared__ int lastflag;
    unsigned int* done = (unsigned int*)&scal[8];
    int t = threadIdx.x;
    int lane = t & 63, w = t >> 6;
    int n0 = blockIdx.x * 64 + w * 16;

    float ps[16];
#pragma unroll
    for (int i = 0; i < 16; ++i) ps[i] = 0.0f;
    float se = 0.0f, cm = 0.0f;

    for (int r = 0; r < 16; ++r) {
        int row = n0 + r;
        const float* ap = aff + (size_t)row * K_CB;
        float4 v[4];
#pragma unroll
        for (int j = 0; j < 4; ++j)
            v[j] = *(const float4*)&ap[j * 256 + lane * 4];

        float m = v[0].x; int mi = lane * 4;
#pragma unroll
        for (int j = 0; j < 4; ++j)
#pragma unroll
            for (int i = 0; i < 4; ++i) {
                float x = ((const float*)&v[j])[i];
                int col = j * 256 + lane * 4 + i;
                if (x > m) { m = x; mi = col; }
            }
#pragma unroll
        for (int off = 32; off > 0; off >>= 1) {
            float vo = __shfl_down(m, off, 64);
            int   io = __shfl_down(mi, off, 64);
            if (vo > m || (vo == m && io < mi)) { m = vo; mi = io; }
        }
        m = __shfl(m, 0, 64);
        mi = __shfl(mi, 0, 64);

        float e[16];
        float S = 0.0f, T = 0.0f;
#pragma unroll
        for (int j = 0; j < 4; ++j)
#pragma unroll
            for (int i = 0; i < 4; ++i) {
                float d = 100.0f * (((const float*)&v[j])[i] - m);
                float ee = __expf(d);
                e[j * 4 + i] = ee; S += ee; T += ee * d;
            }
#pragma unroll
        for (int off = 32; off > 0; off >>= 1) {
            S += __shfl_down(S, off, 64);
            T += __shfl_down(T, off, 64);
        }
        S = __shfl(S, 0, 64);
        T = __shfl(T, 0, 64);
        float invS = 1.0f / S;
#pragma unroll
        for (int i = 0; i < 16; ++i) ps[i] += e[i] * invS;
        se += logf(S) - T * invS;
        cm += 2.0f - 2.0f * m;
        if (lane == 0) out[884737 + row] = (float)mi;

        // gather en[mi] row into transpose buffer (local row = w*16+r)
        float4 g4 = *(const float4*)&en[(size_t)mi * C_DIM + lane * 4];
        int lr = w * 16 + r;
        zq[lr * ZQS + lane * 4 + 0] = g4.x;
        zq[lr * ZQS + lane * 4 + 1] = g4.y;
        zq[lr * ZQS + lane * 4 + 2] = g4.z;
        zq[lr * ZQS + lane * 4 + 3] = g4.w;
    }

    // aggregate ps across waves; write per-block avgp partial (plain stores)
#pragma unroll
    for (int j = 0; j < 4; ++j)
#pragma unroll
        for (int i = 0; i < 4; ++i)
            lps[w][j * 256 + lane * 4 + i] = ps[j * 4 + i];
    if (lane == 0) { lsc[w] = se; lsc[4 + w] = cm; }
    __syncthreads();
#pragma unroll
    for (int c = 0; c < 4; ++c) {
        int col = t * 4 + c;
        avgp_part[(size_t)blockIdx.x * K_CB + col] =
            lps[0][col] + lps[1][col] + lps[2][col] + lps[3][col];
    }
    if (t == 0) atomicAdd(&scal[0], lsc[0] + lsc[1] + lsc[2] + lsc[3]);
    if (t == 1) atomicAdd(&scal[1], lsc[4] + lsc[5] + lsc[6] + lsc[7]);

    // coalesced z_q write: wave handles one col per iter, lanes = 64 rows
    {
        int n = blockIdx.x * 64 + lane;
        int b = n / SPATIAL, s = n - b * SPATIAL;
        size_t obase = ((size_t)b * C_DIM) * SPATIAL + s;
        for (int cc = 0; cc < 64; ++cc) {
            int c = cc * 4 + w;
            out[obase + (size_t)c * SPATIAL] = zq[lane * ZQS + c];
        }
    }

    // last block computes avg-entropy + final loss
    __syncthreads();
    if (t == 0) {
        __threadfence();
        unsigned int old = atomicAdd(done, 1u);
        lastflag = (old == NSB - 1) ? 1 : 0;
    }
    __syncthreads();
    if (lastflag) {
        __threadfence();
        float term = 0.0f;
#pragma unroll
        for (int j = 0; j < 4; ++j) {
            int col = t + 256 * j;
            float ap = 0.0f;
            for (int bb = 0; bb < NSB; ++bb)
                ap += avgp_part[(size_t)bb * K_CB + col];
            ap *= (1.0f / N_ROWS);
            term += ap * logf(ap + 1e-5f);
        }
#pragma unroll
        for (int off = 32; off > 0; off >>= 1) term += __shfl_down(term, off, 64);
        if ((t & 63) == 0) ws4[t >> 6] = term;
        __syncthreads();
        if (t == 0) {
            float sAP = ws4[0] + ws4[1] + ws4[2] + ws4[3];
            float s0 = atomicAdd(&scal[0], 0.0f);
            float s1 = atomicAdd(&scal[1], 0.0f);
            float s2 = atomicAdd(&scal[2], 0.0f);
            float s3 = atomicAdd(&scal[3], 0.0f);
            float sample = s0 * (1.0f / N_ROWS);
            float commit = s1 * (1.0f / ((float)N_ROWS * C_DIM));
            float ent = 0.1f * (sample + sAP);
            float ham = (s2 - s3) / (s2 + 1e-8f);
            out[884736] = 1.25f * commit + ent + ham;
        }
    }
}

// ----------------------------------------------------------------- launch
extern "C" void kernel_launch(void* const* d_in, const int* in_sizes, int n_in,
                              void* d_out, int out_size, void* d_ws, size_t ws_size,
                              hipStream_t stream) {
    const float* in_blocks = (const float*)d_in[0];  // [16,32,24,24,24]
    const float* z_e       = (const float*)d_in[1];  // [16,256,6,6,6]
    const float* cb        = (const float*)d_in[2];  // [1024,256]
    float* out = (float*)d_out;  // [884736 z_q][1 loss][3456 idx]

    char* ws = (char*)d_ws;
    float* en   = (float*)(ws + 0);                  //  1,048,576 B
    float* aff  = (float*)(ws + 1048576);            // 14,155,776 B
    unsigned short* zhi = (unsigned short*)(ws + 15204352);  // 1,769,472 B (swizzled)
    unsigned short* zlo = (unsigned short*)(ws + 16973824);  // 1,769,472 B (swizzled)
    unsigned short* ehi = (unsigned short*)(ws + 18743296);  //   524,288 B (swizzled)
    unsigned short* elo = (unsigned short*)(ws + 19267584);  //   524,288 B (swizzled)
    unsigned long long* pats = (unsigned long long*)(ws + 19791872); // 27,648 B
    float* avgp_part = (float*)(ws + 19819520);      // 54*4096 = 221,184 B
    float* scal = (float*)(ws + 20040704);           // 64 B (scal[0..7] + done)

    k_pre<<<5344, 256, 0, stream>>>(in_blocks, cb, z_e, pats, scal,
                                    en, ehi, elo, zhi, zlo);
    k_mid<<<810, 128, 0, stream>>>(zhi, zlo, ehi, elo, pats, aff, scal);
    k_post<<<NSB, 256, 0, stream>>>(aff, en, avgp_part, scal, out);
}

// Round 8
// 152.540 us; speedup vs baseline: 1.0456x; 1.0456x over previous
//
#include <hip/hip_runtime.h>
#include <cstdint>
#include <cstddef>

#define N_ROWS 3456   // 16*216 chunks
#define C_DIM 256
#define K_CB 1024
#define B_SZ 16
#define SPATIAL 216
#define VOX 13824     // 24*24*24
#define NCH 32
#define NSB 216       // k_post blocks (16 rows each)

typedef __attribute__((ext_vector_type(16))) float f32x16;
typedef __attribute__((ext_vector_type(8))) short bf16x8;

__device__ __forceinline__ unsigned short f2bf_rne(float f) {
    unsigned int u = __float_as_uint(f);
    u += 0x7FFFu + ((u >> 16) & 1u);
    return (unsigned short)(u >> 16);
}
__device__ __forceinline__ float bf2f(unsigned short h) {
    unsigned int u = ((unsigned int)h) << 16;
    return __uint_as_float(u);
}

// Swizzled fragment layout: element (row n, col c) of a [rows x 256] matrix
// lives at  strip(n>>5)*8192 + (c>>3)*256 + (n&31)*8 + (c&7).
// A wave's MFMA fragment for (strip s, k-step s16) is then the contiguous
// 1 KB block  [s*8192 + s16*512 + lane*8 .. +8)  -- 16 B/lane, coalesced.
__device__ __forceinline__ size_t swz(int n, int c) {
    return (size_t)(n >> 5) * 8192 + (size_t)((c >> 3) * 256) + (size_t)((n & 31) * 8) + (c & 7);
}

// ---------------- K1: fused preprocessing: patterns + init + cb/z norm+split
// grid: [0,864) patterns ; [864,1888) codebook ; [1888,5344) z rows
__global__ __launch_bounds__(256) void k_pre(
        const float* __restrict__ in, const float* __restrict__ cb,
        const float* __restrict__ ze,
        unsigned long long* __restrict__ pats,
        float* __restrict__ scal,
        float* __restrict__ en,
        unsigned short* __restrict__ ehi, unsigned short* __restrict__ elo,
        unsigned short* __restrict__ zhi, unsigned short* __restrict__ zlo) {
    int bid = blockIdx.x;
    int t = threadIdx.x;
    if (bid < 864) {
        if (bid == 0 && t < 16) scal[t] = 0.0f;   // scal[0..7] + done counter
        int v = bid * 256 + t;
        int b = v / VOX;
        int r = v % VOX;
        const float* p = in + (size_t)b * NCH * VOX + r;
        float v0 = p[0];
        float mx = -INFINITY;
#pragma unroll
        for (int c = 1; c < NCH; ++c) mx = fmaxf(mx, p[(size_t)c * VOX]);
        unsigned long long m = __ballot(mx > v0);
        if ((t & 63) == 0) pats[v >> 6] = m;
        return;
    }
    __shared__ float ws[4];
    if (bid < 1888) {
        int k = bid - 864, c = t;
        float v = cb[k * C_DIM + c];
        float ss = v * v;
#pragma unroll
        for (int off = 32; off > 0; off >>= 1) ss += __shfl_down(ss, off, 64);
        if ((c & 63) == 0) ws[c >> 6] = ss;
        __syncthreads();
        float nrm = fmaxf(sqrtf(ws[0] + ws[1] + ws[2] + ws[3]), 1e-12f);
        float o = v / nrm;
        en[k * C_DIM + c] = o;
        unsigned short h = f2bf_rne(o);
        size_t off = swz(k, c);
        ehi[off] = h;
        elo[off] = f2bf_rne(o - bf2f(h));
    } else {
        int n = bid - 1888, c = t;
        int b = n / SPATIAL, s = n % SPATIAL;
        float v = ze[((size_t)(b * C_DIM + c)) * SPATIAL + s];
        float ss = v * v;
#pragma unroll
        for (int off = 32; off > 0; off >>= 1) ss += __shfl_down(ss, off, 64);
        if ((c & 63) == 0) ws[c >> 6] = ss;
        __syncthreads();
        float nrm = fmaxf(sqrtf(ws[0] + ws[1] + ws[2] + ws[3]), 1e-12f);
        float o = v / nrm;
        unsigned short h = f2bf_rne(o);
        size_t off = swz(n, c);
        zhi[off] = h;
        zlo[off] = f2bf_rne(o - bf2f(h));
    }
}

// ------------- K2: fat kernel: affinity GEMM (bf16x3 MFMA) + hamming Gram.
// Barrier-free, LDS-free: all fragments loaded directly from the swizzled
// global buffers (coalesced 16 B/lane), latency hidden by unrolled ILP.
// blocks [0,432): gemm 64x128 tiles; [432,810): ham upper-tri 128x128 tiles
__global__ __launch_bounds__(128) void k_mid(
        const unsigned short* __restrict__ zhi, const unsigned short* __restrict__ zlo,
        const unsigned short* __restrict__ ehi, const unsigned short* __restrict__ elo,
        const unsigned long long* __restrict__ pats,
        float* __restrict__ aff, float* __restrict__ scal) {
    int t = threadIdx.x;
    int w = t >> 6, lane = t & 63;
    int bid = blockIdx.x;
    const bf16x8* __restrict__ Zh = (const bf16x8*)zhi;   // [strip][1024 chunks]
    const bf16x8* __restrict__ Zl = (const bf16x8*)zlo;
    const bf16x8* __restrict__ Eh = (const bf16x8*)ehi;
    const bf16x8* __restrict__ El = (const bf16x8*)elo;

    if (bid < 432) {
        // ----- GEMM branch: aff = z @ en^T with hi/lo error compensation
        int ib = bid % 54, jb = bid / 54;
        int i0 = ib * 64, j0 = jb * 128;
        int sa = ib * 2;               // A strips (64 rows = 2 strips)
        int sb = jb * 4 + w * 2;       // B strips for this wave (2 of 4)

        f32x16 acc[2][2];
#pragma unroll
        for (int r = 0; r < 2; ++r)
#pragma unroll
            for (int q = 0; q < 2; ++q)
#pragma unroll
                for (int e = 0; e < 16; ++e) acc[r][q][e] = 0.0f;

#pragma unroll
        for (int s16 = 0; s16 < 16; ++s16) {    // 16 k-steps of 16
            int u = s16 * 64 + lane;
            bf16x8 ah[2], al[2], bh[2], bl[2];
#pragma unroll
            for (int r = 0; r < 2; ++r) {
                ah[r] = Zh[(size_t)(sa + r) * 1024 + u];
                al[r] = Zl[(size_t)(sa + r) * 1024 + u];
            }
#pragma unroll
            for (int q = 0; q < 2; ++q) {
                bh[q] = Eh[(size_t)(sb + q) * 1024 + u];
                bl[q] = El[(size_t)(sb + q) * 1024 + u];
            }
#pragma unroll
            for (int r = 0; r < 2; ++r)
#pragma unroll
                for (int q = 0; q < 2; ++q) {
                    acc[r][q] = __builtin_amdgcn_mfma_f32_32x32x16_bf16(ah[r], bh[q], acc[r][q], 0, 0, 0);
                    acc[r][q] = __builtin_amdgcn_mfma_f32_32x32x16_bf16(ah[r], bl[q], acc[r][q], 0, 0, 0);
                    acc[r][q] = __builtin_amdgcn_mfma_f32_32x32x16_bf16(al[r], bh[q], acc[r][q], 0, 0, 0);
                }
        }
        // C/D layout (m74/m101): col=lane&31, row=(g&3)+8*(g>>2)+4*(lane>>5)
#pragma unroll
        for (int r = 0; r < 2; ++r)
#pragma unroll
            for (int q = 0; q < 2; ++q)
#pragma unroll
                for (int g = 0; g < 16; ++g) {
                    int row = i0 + r * 32 + (g & 3) + 8 * (g >> 2) + 4 * (lane >> 5);
                    int col = j0 + w * 64 + q * 32 + (lane & 31);
                    aff[(size_t)row * K_CB + col] = acc[r][q][g];
                }
        return;
    }

    // ----- HAM branch: pairwise Gram, upper-triangular 128x128 tiles
    int hb = bid - 432;              // 0..377
    int ti = 0, rem = hb;
    while (rem >= 27 - ti) { rem -= 27 - ti; ++ti; }
    int tj = ti + rem;
    int i0 = ti * 128, j0 = tj * 128;
    float factor = (ti == tj) ? 1.0f : 2.0f;
    int si = ti * 4 + w * 2;         // A strips for this wave (2 of 4)
    int sj = tj * 4;                 // B strips (4)

    f32x16 acc[2][4];
#pragma unroll
    for (int a = 0; a < 2; ++a)
#pragma unroll
        for (int b = 0; b < 4; ++b)
#pragma unroll
            for (int e = 0; e < 16; ++e) acc[a][b][e] = 0.0f;

#pragma unroll
    for (int s16 = 0; s16 < 16; ++s16) {
        int u = s16 * 64 + lane;
        bf16x8 a0 = Zh[(size_t)si * 1024 + u];
        bf16x8 a1 = Zh[(size_t)(si + 1) * 1024 + u];
        bf16x8 bf[4];
#pragma unroll
        for (int c = 0; c < 4; ++c)
            bf[c] = Zh[(size_t)(sj + c) * 1024 + u];
#pragma unroll
        for (int c = 0; c < 4; ++c) {
            acc[0][c] = __builtin_amdgcn_mfma_f32_32x32x16_bf16(a0, bf[c], acc[0][c], 0, 0, 0);
            acc[1][c] = __builtin_amdgcn_mfma_f32_32x32x16_bf16(a1, bf[c], acc[1][c], 0, 0, 0);
        }
    }

    unsigned long long pj[4];
#pragma unroll
    for (int c = 0; c < 4; ++c) pj[c] = pats[j0 + c * 32 + (lane & 31)];

    float sW = 0.0f, sD = 0.0f;
#pragma unroll
    for (int r = 0; r < 2; ++r) {
        int ibase = i0 + w * 64 + r * 32 + 4 * (lane >> 5);
#pragma unroll
        for (int g = 0; g < 16; ++g) {
            int gi = ibase + (g & 3) + 8 * (g >> 2);
            unsigned long long pi = pats[gi];
#pragma unroll
            for (int c = 0; c < 4; ++c) {
                int gj = j0 + c * 32 + (lane & 31);
                int pop = __popcll(pi ^ pj[c]);
                float wgt = (pop <= 5 && gi != gj) ? (1.0f - (float)pop * 0.015625f) : 0.0f;
                sW += wgt;
                sD += wgt * acc[r][c][g];
            }
        }
    }
#pragma unroll
    for (int off = 32; off > 0; off >>= 1) {
        sW += __shfl_down(sW, off, 64);
        sD += __shfl_down(sD, off, 64);
    }
    if (lane == 0) {
        atomicAdd(&scal[2], factor * sW);
        atomicAdd(&scal[3], factor * sD);
    }
}

// -------- K3: stats + z_q gather/scatter + final loss (last-block reduce)
// 216 blocks x 16 rows; wave = 4 rows; lane owns 16 cols of each row.
#define ZQS 257
__global__ __launch_bounds__(256) void k_post(
        const float* __restrict__ aff, const float* __restrict__ en,
        float* __restrict__ avgp_part, float* __restrict__ scal,
        float* __restrict__ out) {
    __shared__ float lps[4][K_CB];       // 16 KB
    __shared__ float zq[16 * ZQS];       // 16.4 KB transpose buffer
    __shared__ float lsc[8];
    __shared__ float ws4[4];
    __shared__ int lastflag;
    unsigned int* done = (unsigned int*)&scal[8];
    int t = threadIdx.x;
    int lane = t & 63, w = t >> 6;
    int n0 = blockIdx.x * 16;

    float ps[16];
#pragma unroll
    for (int i = 0; i < 16; ++i) ps[i] = 0.0f;
    float se = 0.0f, cm = 0.0f;

#pragma unroll
    for (int r = 0; r < 4; ++r) {
        int lr = w * 4 + r;              // local row 0..15
        int row = n0 + lr;
        const float* ap = aff + (size_t)row * K_CB;
        float4 v[4];
#pragma unroll
        for (int j = 0; j < 4; ++j)
            v[j] = *(const float4*)&ap[j * 256 + lane * 4];

        float m = v[0].x; int mi = lane * 4;
#pragma unroll
        for (int j = 0; j < 4; ++j)
#pragma unroll
            for (int i = 0; i < 4; ++i) {
                float x = ((const float*)&v[j])[i];
                int col = j * 256 + lane * 4 + i;
                if (x > m) { m = x; mi = col; }
            }
#pragma unroll
        for (int off = 32; off > 0; off >>= 1) {
            float vo = __shfl_down(m, off, 64);
            int   io = __shfl_down(mi, off, 64);
            if (vo > m || (vo == m && io < mi)) { m = vo; mi = io; }
        }
        m = __shfl(m, 0, 64);
        mi = __shfl(mi, 0, 64);

        float e[16];
        float S = 0.0f, T = 0.0f;
#pragma unroll
        for (int j = 0; j < 4; ++j)
#pragma unroll
            for (int i = 0; i < 4; ++i) {
                float d = 100.0f * (((const float*)&v[j])[i] - m);
                float ee = __expf(d);
                e[j * 4 + i] = ee; S += ee; T += ee * d;
            }
#pragma unroll
        for (int off = 32; off > 0; off >>= 1) {
            S += __shfl_down(S, off, 64);
            T += __shfl_down(T, off, 64);
        }
        S = __shfl(S, 0, 64);
        T = __shfl(T, 0, 64);
        float invS = 1.0f / S;
#pragma unroll
        for (int i = 0; i < 16; ++i) ps[i] += e[i] * invS;
        se += logf(S) - T * invS;
        cm += 2.0f - 2.0f * m;
        if (lane == 0) out[884737 + row] = (float)mi;

        // gather en[mi] row into transpose buffer
        float4 g4 = *(const float4*)&en[(size_t)mi * C_DIM + lane * 4];
        zq[lr * ZQS + lane * 4 + 0] = g4.x;
        zq[lr * ZQS + lane * 4 + 1] = g4.y;
        zq[lr * ZQS + lane * 4 + 2] = g4.z;
        zq[lr * ZQS + lane * 4 + 3] = g4.w;
    }

    // aggregate ps across waves; write per-block avgp partial (plain stores)
#pragma unroll
    for (int j = 0; j < 4; ++j)
#pragma unroll
        for (int i = 0; i < 4; ++i)
            lps[w][j * 256 + lane * 4 + i] = ps[j * 4 + i];
    if (lane == 0) { lsc[w] = se; lsc[4 + w] = cm; }
    __syncthreads();
#pragma unroll
    for (int c = 0; c < 4; ++c) {
        int col = t * 4 + c;
        avgp_part[(size_t)blockIdx.x * K_CB + col] =
            lps[0][col] + lps[1][col] + lps[2][col] + lps[3][col];
    }
    if (t == 0) atomicAdd(&scal[0], lsc[0] + lsc[1] + lsc[2] + lsc[3]);
    if (t == 1) atomicAdd(&scal[1], lsc[4] + lsc[5] + lsc[6] + lsc[7]);

    // z_q write: thread t -> (row rlane = t&15, col group cgrp = t>>4).
    // 16 consecutive s per 16-thread group = 64 B segments.
    {
        int rlane = t & 15, cgrp = t >> 4;
        int n = n0 + rlane;
        int b = n / SPATIAL, s = n - b * SPATIAL;
        size_t obase = ((size_t)b * C_DIM) * SPATIAL + s;
#pragma unroll
        for (int cc = 0; cc < 16; ++cc) {
            int c = cgrp * 16 + cc;
            out[obase + (size_t)c * SPATIAL] = zq[rlane * ZQS + c];
        }
    }

    // last block computes avg-entropy + final loss
    __syncthreads();
    if (t == 0) {
        __threadfence();
        unsigned int old = atomicAdd(done, 1u);
        lastflag = (old == NSB - 1) ? 1 : 0;
    }
    __syncthreads();
    if (lastflag) {
        __threadfence();
        float4 apv = make_float4(0.0f, 0.0f, 0.0f, 0.0f);
        for (int bb = 0; bb < NSB; ++bb) {
            float4 pv = *(const float4*)&avgp_part[(size_t)bb * K_CB + t * 4];
            apv.x += pv.x; apv.y += pv.y; apv.z += pv.z; apv.w += pv.w;
        }
        float term = 0.0f;
#pragma unroll
        for (int i = 0; i < 4; ++i) {
            float ap = ((const float*)&apv)[i] * (1.0f / N_ROWS);
            term += ap * logf(ap + 1e-5f);
        }
#pragma unroll
        for (int off = 32; off > 0; off >>= 1) term += __shfl_down(term, off, 64);
        if ((t & 63) == 0) ws4[t >> 6] = term;
        __syncthreads();
        if (t == 0) {
            float sAP = ws4[0] + ws4[1] + ws4[2] + ws4[3];
            float s0 = atomicAdd(&scal[0], 0.0f);
            float s1 = atomicAdd(&scal[1], 0.0f);
            float s2 = atomicAdd(&scal[2], 0.0f);
            float s3 = atomicAdd(&scal[3], 0.0f);
            float sample = s0 * (1.0f / N_ROWS);
            float commit = s1 * (1.0f / ((float)N_ROWS * C_DIM));
            float ent = 0.1f * (sample + sAP);
            float ham = (s2 - s3) / (s2 + 1e-8f);
            out[884736] = 1.25f * commit + ent + ham;
        }
    }
}

// ----------------------------------------------------------------- launch
extern "C" void kernel_launch(void* const* d_in, const int* in_sizes, int n_in,
                              void* d_out, int out_size, void* d_ws, size_t ws_size,
                              hipStream_t stream) {
    const float* in_blocks = (const float*)d_in[0];  // [16,32,24,24,24]
    const float* z_e       = (const float*)d_in[1];  // [16,256,6,6,6]
    const float* cb        = (const float*)d_in[2];  // [1024,256]
    float* out = (float*)d_out;  // [884736 z_q][1 loss][3456 idx]

    char* ws = (char*)d_ws;
    float* en   = (float*)(ws + 0);                  //  1,048,576 B
    float* aff  = (float*)(ws + 1048576);            // 14,155,776 B
    unsigned short* zhi = (unsigned short*)(ws + 15204352);  // 1,769,472 B (swizzled)
    unsigned short* zlo = (unsigned short*)(ws + 16973824);  // 1,769,472 B (swizzled)
    unsigned short* ehi = (unsigned short*)(ws + 18743296);  //   524,288 B (swizzled)
    unsigned short* elo = (unsigned short*)(ws + 19267584);  //   524,288 B (swizzled)
    unsigned long long* pats = (unsigned long long*)(ws + 19791872); // 27,648 B
    float* avgp_part = (float*)(ws + 19819520);      // 216*4096 = 884,736 B
    float* scal = (float*)(ws + 20704256);           // 64 B (scal[0..7] + done)

    k_pre<<<5344, 256, 0, stream>>>(in_blocks, cb, z_e, pats, scal,
                                    en, ehi, elo, zhi, zlo);
    k_mid<<<810, 128, 0, stream>>>(zhi, zlo, ehi, elo, pats, aff, scal);
    k_post<<<NSB, 256, 0, stream>>>(aff, en, avgp_part, scal, out);
}